// Round 1
// baseline (376.192 us; speedup 1.0000x reference)
//
#include <hip/hip_runtime.h>

// Problem constants (fixed by setup_inputs)
#define T_TOK 8192
#define D_HID 1280
#define H_    16
#define HD_   80
#define C_    8
#define L_    1024
#define N3_   3840
#define QPAD  96     // Q/K head-dim padded to 96 (3 x K=32 MFMA steps)

typedef _Float16 f16;
typedef __attribute__((ext_vector_type(8))) _Float16 h8;   // MFMA A/B frag (4 VGPR)
typedef __attribute__((ext_vector_type(4))) float f32x4;   // MFMA C/D frag

// ---------------------------------------------------------------------------
// convert_x: fp32 -> fp16, same layout. 4 elems/thread.
// ---------------------------------------------------------------------------
__global__ __launch_bounds__(256) void convert_x(const float* __restrict__ x,
                                                 f16* __restrict__ y) {
  const int g = blockIdx.x * 256 + threadIdx.x;
  const float4 v = ((const float4*)x)[g];
  f16 o[4] = {(f16)v.x, (f16)v.y, (f16)v.z, (f16)v.w};
  ((uint2*)y)[g] = *(const uint2*)o;
}

// ---------------------------------------------------------------------------
// convert_w_t: W[K][N] fp32 -> Wt[N][K] fp16 (transposed for B^T GEMM).
// ---------------------------------------------------------------------------
__global__ __launch_bounds__(256) void convert_w_t(const float* __restrict__ W,
                                                   f16* __restrict__ Wt,
                                                   int K, int N) {
  __shared__ float tile[32][33];
  const int n0 = blockIdx.x * 32, k0 = blockIdx.y * 32;
  const int c = threadIdx.x & 31, r0 = threadIdx.x >> 5;
#pragma unroll
  for (int it = 0; it < 4; ++it) {
    const int r = r0 + it * 8;
    tile[r][c] = W[(size_t)(k0 + r) * N + n0 + c];
  }
  __syncthreads();
#pragma unroll
  for (int it = 0; it < 4; ++it) {
    const int r = r0 + it * 8;
    Wt[(size_t)(n0 + r) * K + k0 + c] = (f16)tile[c][r];
  }
}

// ---------------------------------------------------------------------------
// gemm_f16: C = A @ B^T + bias, fp16 in, fp32 MFMA accumulate.
// Block tile 128x256, BK=64. 4 waves; each wave owns a 64x128 C-tile
// (4x8 16x16 tiles, 128 acc VGPRs). Staging via global_load_lds w16 with
// the XOR swizzle (measured 0 bank conflicts). Unchanged from the 401 µs
// baseline; 8-phase port is the planned next structural change.
// ---------------------------------------------------------------------------
__device__ __forceinline__ void stage_rows(const f16* __restrict__ gbase, int K,
                                           f16* sdst, int nchunks, int tid) {
  // nchunks = rows*8, each 16B; 256 threads
  for (int s0 = 0; s0 < nchunks; s0 += 256) {
    const int s = s0 + tid;
    const int row = s >> 3;
    const int part = (s & 7) ^ (row & 7);           // XOR swizzle
    const f16* gp = gbase + (size_t)row * K + part * 8;
    __builtin_amdgcn_global_load_lds(
        (const __attribute__((address_space(1))) void*)gp,
        (__attribute__((address_space(3))) void*)(sdst + s * 8),
        16, 0, 0);
  }
}

__device__ __forceinline__ h8 fragld64(const f16* s, int row, int c) {
  const int slot = c ^ (row & 7);                   // c = ks*4 + quad
  return *(const h8*)&s[row * 64 + slot * 8];
}

__global__ __launch_bounds__(256, 2) void gemm_f16(
    const f16* __restrict__ A, const f16* __restrict__ B,
    const float* __restrict__ bias,
    float* __restrict__ Cf, f16* __restrict__ Ch,
    int M, int N, int K) {
  __shared__ f16 sA[128 * 64], sB[256 * 64];
  const int tid = threadIdx.x;
  const int wave = tid >> 6, lane = tid & 63;
  const int quad = lane >> 4, ln = lane & 15;
  const int bm = blockIdx.y * 128, bn = blockIdx.x * 256;
  const int wm = (wave >> 1) * 64, wn = (wave & 1) * 128;

  f32x4 acc[4][8];
#pragma unroll
  for (int i = 0; i < 4; ++i)
#pragma unroll
    for (int j = 0; j < 8; ++j) acc[i][j] = (f32x4){0.f, 0.f, 0.f, 0.f};

  for (int k0 = 0; k0 < K; k0 += 64) {
    __syncthreads();
    stage_rows(A + (size_t)bm * K + k0, K, sA, 128 * 8, tid);
    stage_rows(B + (size_t)bn * K + k0, K, sB, 256 * 8, tid);
    __syncthreads();

#pragma unroll
    for (int ks = 0; ks < 2; ++ks) {
      h8 af[4], bf[8];
#pragma unroll
      for (int i = 0; i < 4; ++i) af[i] = fragld64(sA, wm + i * 16 + ln, ks * 4 + quad);
#pragma unroll
      for (int j = 0; j < 8; ++j) bf[j] = fragld64(sB, wn + j * 16 + ln, ks * 4 + quad);
#pragma unroll
      for (int i = 0; i < 4; ++i)
#pragma unroll
        for (int j = 0; j < 8; ++j)
          acc[i][j] = __builtin_amdgcn_mfma_f32_16x16x32_f16(af[i], bf[j], acc[i][j], 0, 0, 0);
    }
  }

  float bv[8];
#pragma unroll
  for (int j = 0; j < 8; ++j) bv[j] = bias[bn + wn + j * 16 + ln];
#pragma unroll
  for (int i = 0; i < 4; ++i)
#pragma unroll
    for (int j = 0; j < 8; ++j)
#pragma unroll
      for (int r = 0; r < 4; ++r) {
        const int row = bm + wm + i * 16 + quad * 4 + r;   // C: row=quad*4+reg
        const int col = bn + wn + j * 16 + ln;             //    col=lane&15
        const float val = acc[i][j][r] + bv[j];
        if (Ch) Ch[(size_t)row * N + col] = (f16)val;
        else    Cf[(size_t)row * N + col] = val;
      }
}

// ---------------------------------------------------------------------------
// rope_convert: fp16 qkv -> RoPE'd Qb/Kb, head-major [h][t][96] ZERO-PADDED
// (cols 80..95). Softmax scale folded into Qb.
// Vectorized (G13): one wave per token; 8-f16 chunks. rotate_half partner of
// an aligned 8-chunk is an aligned 8-chunk (40 % 8 == 0), so int4 loads on
// both sides; float4 cos/sin; int4 stores.
// ---------------------------------------------------------------------------
__global__ __launch_bounds__(256) void rope_convert(
    const f16* __restrict__ qkv, const float* __restrict__ cosb,
    const float* __restrict__ sinb, f16* __restrict__ Qb, f16* __restrict__ Kb) {
  const int tid = threadIdx.x;
  const int wave = tid >> 6, lane = tid & 63;
  const int t = blockIdx.x * 4 + wave;
  const size_t rowb = (size_t)t * N3_;
  const float qscale = 0.11180339887498949f;
#pragma unroll
  for (int u = 0; u < 5; ++u) {
    const int g = u * 64 + lane;          // chunk id 0..319 within token
    const int e = g * 8;                  // element 0..2552 (q then k)
    const int d = e % HD_;                // multiple of 8
    const int h = (e % D_HID) / HD_;
    const bool isK = e >= D_HID;
    const bool lo = d < 40;
    const int pe = lo ? e + 40 : e - 40;  // rotate_half partner chunk
    f16 v[8], p[8];
    *(int4*)v = *(const int4*)(qkv + rowb + e);
    *(int4*)p = *(const int4*)(qkv + rowb + pe);
    const float4 cs0 = *(const float4*)(cosb + (size_t)t * HD_ + d);
    const float4 cs1 = *(const float4*)(cosb + (size_t)t * HD_ + d + 4);
    const float4 sn0 = *(const float4*)(sinb + (size_t)t * HD_ + d);
    const float4 sn1 = *(const float4*)(sinb + (size_t)t * HD_ + d + 4);
    const float cs[8] = {cs0.x, cs0.y, cs0.z, cs0.w, cs1.x, cs1.y, cs1.z, cs1.w};
    const float sn[8] = {sn0.x, sn0.y, sn0.z, sn0.w, sn1.x, sn1.y, sn1.z, sn1.w};
    f16 o[8];
#pragma unroll
    for (int j = 0; j < 8; ++j) {
      const float pv = lo ? -(float)p[j] : (float)p[j];
      const float ov = (float)v[j] * cs[j] + pv * sn[j];
      o[j] = (f16)(isK ? ov : ov * qscale);
    }
    *(int4*)((isK ? Kb : Qb) + ((size_t)h * T_TOK + t) * QPAD + d) = *(const int4*)o;
  }
  // zero pad columns 80..95 (ws is poisoned): 64 lanes = 2(qk) x 16(h) x 2(half)
  {
    const int qk = lane >> 5, h = (lane >> 1) & 15, half = lane & 1;
    f16* dst = (qk ? Kb : Qb) + ((size_t)h * T_TOK + t) * QPAD + 80 + half * 8;
    *(int4*)dst = make_int4(0, 0, 0, 0);
  }
}

// ---------------------------------------------------------------------------
// vt_convert: v (fp16, cols 2560..3839 of qkv) -> Vt[h][d][t] (transposed).
// ---------------------------------------------------------------------------
__global__ __launch_bounds__(256) void vt_convert(const f16* __restrict__ qkv,
                                                  f16* __restrict__ Vt) {
  __shared__ f16 tl[HD_][136];
  const int h = blockIdx.x & 15;
  const int t0 = (blockIdx.x >> 4) * 128;
  const int tid = threadIdx.x;
#pragma unroll
  for (int it = 0; it < 5; ++it) {
    const int e = tid + it * 256;
    const int t = e / 10, pc = e % 10;
    int4 v = *(const int4*)(qkv + (size_t)(t0 + t) * N3_ + 2 * D_HID + h * HD_ + pc * 8);
    f16 tmp[8];
    *(int4*)tmp = v;
#pragma unroll
    for (int u = 0; u < 8; ++u) tl[pc * 8 + u][t] = tmp[u];
  }
  __syncthreads();
#pragma unroll
  for (int it = 0; it < 5; ++it) {
    const int e = tid + it * 256;
    const int d = e >> 4, pt = e & 15;
    *(int4*)(Vt + ((size_t)h * HD_ + d) * T_TOK + t0 + pt * 8) = *(const int4*)&tl[d][pt * 8];
  }
}

// ---------------------------------------------------------------------------
// attn_flash: BARRIER-FREE flash attention. T5 setprio added around the
// MFMA clusters (barrier-free waves at different phases = m191 regime).
// ---------------------------------------------------------------------------
__global__ __launch_bounds__(256, 2) void attn_flash(
    const f16* __restrict__ Qb, const f16* __restrict__ Kb,
    const f16* __restrict__ Vt, f16* __restrict__ Oa) {
  __shared__ f16 Ps[4][64][72];              // per-wave P tile, stride 72
  const int tid = threadIdx.x;
  const int wave = tid >> 6, lane = tid & 63;
  const int quad = lane >> 4, ln = lane & 15;
  const int h = blockIdx.x & 15;
  const int qb = (blockIdx.x >> 4) & 3;
  const int c = blockIdx.x >> 6;
  const int t0 = c * L_ + qb * 256 + wave * 64;
  const size_t hb = (size_t)h * T_TOK;

  h8 aq[4][3];
#pragma unroll
  for (int i = 0; i < 4; ++i)
#pragma unroll
    for (int ks = 0; ks < 3; ++ks)
      aq[i][ks] = *(const h8*)(Qb + (hb + t0 + i * 16 + ln) * QPAD + ks * 32 + quad * 8);

  f32x4 o[4][5];
  float lsum[4][4];
#pragma unroll
  for (int i = 0; i < 4; ++i) {
#pragma unroll
    for (int jn = 0; jn < 5; ++jn) o[i][jn] = (f32x4){0.f, 0.f, 0.f, 0.f};
#pragma unroll
    for (int r = 0; r < 4; ++r) lsum[i][r] = 0.f;
  }

  for (int kb = 0; kb < 16; ++kb) {
    const int kt0 = c * L_ + kb * 64;
#pragma unroll
    for (int j = 0; j < 4; ++j) {
      h8 bk[3];
#pragma unroll
      for (int ks = 0; ks < 3; ++ks)
        bk[ks] = *(const h8*)(Kb + (hb + kt0 + j * 16 + ln) * QPAD + ks * 32 + quad * 8);
      f32x4 s[4];
#pragma unroll
      for (int i = 0; i < 4; ++i) s[i] = (f32x4){0.f, 0.f, 0.f, 0.f};
      __builtin_amdgcn_s_setprio(1);
#pragma unroll
      for (int ks = 0; ks < 3; ++ks)
#pragma unroll
        for (int i = 0; i < 4; ++i)
          s[i] = __builtin_amdgcn_mfma_f32_16x16x32_f16(aq[i][ks], bk[ks], s[i], 0, 0, 0);
      __builtin_amdgcn_s_setprio(0);
#pragma unroll
      for (int i = 0; i < 4; ++i)
#pragma unroll
        for (int r = 0; r < 4; ++r) {
          const float p = __expf(s[i][r]);
          lsum[i][r] += p;
          Ps[wave][i * 16 + quad * 4 + r][j * 16 + ln] = (f16)p;
        }
    }
#pragma unroll
    for (int ks = 0; ks < 2; ++ks) {
      h8 ap[4];
#pragma unroll
      for (int i = 0; i < 4; ++i)
        ap[i] = *(const h8*)&Ps[wave][i * 16 + ln][ks * 32 + quad * 8];
#pragma unroll
      for (int jn = 0; jn < 5; ++jn) {
        const h8 bv = *(const h8*)(Vt + ((size_t)h * HD_ + jn * 16 + ln) * T_TOK
                                   + kt0 + ks * 32 + quad * 8);
        __builtin_amdgcn_s_setprio(1);
#pragma unroll
        for (int i = 0; i < 4; ++i)
          o[i][jn] = __builtin_amdgcn_mfma_f32_16x16x32_f16(ap[i], bv, o[i][jn], 0, 0, 0);
        __builtin_amdgcn_s_setprio(0);
      }
    }
  }

#pragma unroll
  for (int i = 0; i < 4; ++i)
#pragma unroll
    for (int r = 0; r < 4; ++r) {
      float s = lsum[i][r];
#pragma unroll
      for (int off = 1; off < 16; off <<= 1) s += __shfl_xor(s, off);
      lsum[i][r] = 1.f / s;
    }

#pragma unroll
  for (int i = 0; i < 4; ++i)
#pragma unroll
    for (int r = 0; r < 4; ++r) {
      const int t = t0 + i * 16 + quad * 4 + r;
      const float inv = lsum[i][r];
#pragma unroll
      for (int jn = 0; jn < 5; ++jn)
        Oa[(size_t)t * D_HID + h * HD_ + jn * 16 + ln] = (f16)(o[i][jn][r] * inv);
    }
}

// ---------------------------------------------------------------------------
extern "C" void kernel_launch(void* const* d_in, const int* in_sizes, int n_in,
                              void* d_out, int out_size, void* d_ws, size_t ws_size,
                              hipStream_t stream) {
  (void)in_sizes; (void)n_in; (void)out_size; (void)ws_size;
  const float* x      = (const float*)d_in[0];
  const float* cosb   = (const float*)d_in[1];
  const float* sinb   = (const float*)d_in[2];
  const float* w_qkv  = (const float*)d_in[3];
  const float* b_qkv  = (const float*)d_in[4];
  const float* w_proj = (const float*)d_in[5];
  const float* b_proj = (const float*)d_in[6];
  float* out = (float*)d_out;

  // workspace map (bytes):
  //  [0)           qkv f16    62,914,560  } aliased by attn O (21 MB) post-vt
  //  [62914560)    Qb [16][8192][96]  25,165,824
  //  [88080384)    Kb [16][8192][96]  25,165,824
  //  [113246208)   Vt [16][80][8192]  20,971,520
  //  [134217728)   Wqkv_t              9,830,400
  //  [144048128)   Wproj_t             3,276,800   -> end 147,324,928
  char* ws = (char*)d_ws;
  f16* qkv_h  = (f16*)(ws);
  f16* attn_h = (f16*)(ws);                          // alias (post-attention)
  f16* x_h    = (f16*)(ws + 62914560);               // temp in Qb slot
  f16* Qb     = (f16*)(ws + 62914560);               // alias (post-GEMM1)
  f16* Kb     = (f16*)(ws + 88080384);
  f16* Vt     = (f16*)(ws + 113246208);
  f16* wq_t   = (f16*)(ws + 134217728);
  f16* wp_t   = (f16*)(ws + 144048128);

  // 1) fp16 conversions (X, W^T)
  convert_x<<<(T_TOK * D_HID / 4) / 256, 256, 0, stream>>>(x, x_h);
  convert_w_t<<<dim3(N3_ / 32, D_HID / 32), 256, 0, stream>>>(w_qkv, wq_t, D_HID, N3_);
  convert_w_t<<<dim3(D_HID / 32, D_HID / 32), 256, 0, stream>>>(w_proj, wp_t, D_HID, D_HID);
  // 2) qkv = x @ w_qkv + b_qkv  (fp16 out)
  gemm_f16<<<dim3(N3_ / 256, T_TOK / 128), 256, 0, stream>>>(
      x_h, wq_t, b_qkv, nullptr, qkv_h, T_TOK, N3_, D_HID);
  // 3) RoPE + head-major padded fp16 Q/K (scale folded into Q), 1 wave/token
  rope_convert<<<T_TOK / 4, 256, 0, stream>>>(qkv_h, cosb, sinb, Qb, Kb);
  // 4) V transpose to [h][d][t]
  vt_convert<<<H_ * (T_TOK / 128), 256, 0, stream>>>(qkv_h, Vt);
  // 5) barrier-free flash attention -> attn fp16 [t][1280]
  attn_flash<<<C_ * 4 * H_, 256, 0, stream>>>(Qb, Kb, Vt, attn_h);
  // 6) out = attn @ w_proj + b_proj  (fp32 out)
  gemm_f16<<<dim3(D_HID / 256, T_TOK / 128), 256, 0, stream>>>(
      attn_h, wp_t, b_proj, out, nullptr, T_TOK, D_HID, D_HID);
}

// Round 2
// 375.819 us; speedup vs baseline: 1.0010x; 1.0010x over previous
//
#include <hip/hip_runtime.h>

// Problem constants (fixed by setup_inputs)
#define T_TOK 8192
#define D_HID 1280
#define H_    16
#define HD_   80
#define C_    8
#define L_    1024
#define N3_   3840
#define QPAD  96     // Q/K head-dim padded to 96 (3 x K=32 MFMA steps)

typedef _Float16 f16;
typedef __attribute__((ext_vector_type(8))) _Float16 h8;   // MFMA A/B frag (4 VGPR)
typedef __attribute__((ext_vector_type(4))) float f32x4;   // MFMA C/D frag

// ---------------------------------------------------------------------------
// convert_x: fp32 -> fp16, same layout. 4 elems/thread.
// ---------------------------------------------------------------------------
__global__ __launch_bounds__(256) void convert_x(const float* __restrict__ x,
                                                 f16* __restrict__ y) {
  const int g = blockIdx.x * 256 + threadIdx.x;
  const float4 v = ((const float4*)x)[g];
  f16 o[4] = {(f16)v.x, (f16)v.y, (f16)v.z, (f16)v.w};
  ((uint2*)y)[g] = *(const uint2*)o;
}

// ---------------------------------------------------------------------------
// convert_w_t: W[K][N] fp32 -> Wt[N][K] fp16 (transposed for B^T GEMM).
// ---------------------------------------------------------------------------
__global__ __launch_bounds__(256) void convert_w_t(const float* __restrict__ W,
                                                   f16* __restrict__ Wt,
                                                   int K, int N) {
  __shared__ float tile[32][33];
  const int n0 = blockIdx.x * 32, k0 = blockIdx.y * 32;
  const int c = threadIdx.x & 31, r0 = threadIdx.x >> 5;
#pragma unroll
  for (int it = 0; it < 4; ++it) {
    const int r = r0 + it * 8;
    tile[r][c] = W[(size_t)(k0 + r) * N + n0 + c];
  }
  __syncthreads();
#pragma unroll
  for (int it = 0; it < 4; ++it) {
    const int r = r0 + it * 8;
    Wt[(size_t)(n0 + r) * K + k0 + c] = (f16)tile[c][r];
  }
}

// ---------------------------------------------------------------------------
// gemm_f16: C = A @ B^T + bias, fp16 in, fp32 MFMA accumulate.
// R2: 256x256 tile, BK=64, 512 threads (8 waves 2x4, each owns 128x64 C).
// Double-buffered 128 KiB LDS, counted-vmcnt pipeline (T3/T4):
//   STAGE(t+1) -> s_waitcnt vmcnt(8) -> s_barrier -> ds_read+MFMA -> s_barrier
// Raw s_barrier (NOT __syncthreads) so prefetch loads stay in flight across
// the barrier; exactly 8 global_load_lds/thread per K-tile so vmcnt(8) waits
// precisely for tile t while t+1 streams. XOR swizzle unchanged (0 conflicts).
// XCD-chunked block swizzle (nwg % 8 == 0 for both GEMMs).
// ---------------------------------------------------------------------------
__device__ __forceinline__ void stage_rows512(const f16* __restrict__ gbase, int K,
                                              f16* sdst, int tid) {
  // 256 rows x 64 cols fp16 = 2048 x 16B chunks; 512 threads -> 4 each
#pragma unroll
  for (int s0 = 0; s0 < 2048; s0 += 512) {
    const int s = s0 + tid;
    const int row = s >> 3;
    const int part = (s & 7) ^ (row & 7);           // XOR swizzle
    const f16* gp = gbase + (size_t)row * K + part * 8;
    __builtin_amdgcn_global_load_lds(
        (const __attribute__((address_space(1))) void*)gp,
        (__attribute__((address_space(3))) void*)(sdst + s * 8),
        16, 0, 0);
  }
}

__device__ __forceinline__ h8 fragld64(const f16* s, int row, int c) {
  const int slot = c ^ (row & 7);                   // c = ks*4 + quad
  return *(const h8*)&s[row * 64 + slot * 8];
}

__global__ __launch_bounds__(512, 2) void gemm_f16(
    const f16* __restrict__ A, const f16* __restrict__ B,
    const float* __restrict__ bias,
    float* __restrict__ Cf, f16* __restrict__ Ch,
    int M, int N, int K) {
  __shared__ f16 sAB[2][2][256 * 64];               // 128 KiB, dbuf x {A,B}
  const int tid = threadIdx.x;
  const int wave = tid >> 6, lane = tid & 63;
  const int quad = lane >> 4, ln = lane & 15;

  // XCD-chunked bijective swizzle (nwg % 8 == 0: 480 / 160)
  const int nwg = gridDim.x;
  int wg = blockIdx.x;
  wg = (wg & 7) * (nwg >> 3) + (wg >> 3);
  const int nbx = N >> 8;
  const int bm = (wg / nbx) * 256, bn = (wg % nbx) * 256;
  const int wm = (wave >> 2) * 128, wn = (wave & 3) * 64;

  f32x4 acc[8][4];
#pragma unroll
  for (int i = 0; i < 8; ++i)
#pragma unroll
    for (int j = 0; j < 4; ++j) acc[i][j] = (f32x4){0.f, 0.f, 0.f, 0.f};

  const f16* Abase = A + (size_t)bm * K;
  const f16* Bbase = B + (size_t)bn * K;

  // prologue: stage tile 0 (8 loads/thread)
  stage_rows512(Abase, K, sAB[0][0], tid);
  stage_rows512(Bbase, K, sAB[0][1], tid);

  const int nt = K >> 6;
  for (int t = 0; t < nt; ++t) {
    if (t + 1 < nt) {
      // issue tile t+1 (8 more loads in flight), then wait only for tile t
      stage_rows512(Abase + (t + 1) * 64, K, sAB[(t + 1) & 1][0], tid);
      stage_rows512(Bbase + (t + 1) * 64, K, sAB[(t + 1) & 1][1], tid);
      asm volatile("s_waitcnt vmcnt(8)" ::: "memory");
    } else {
      asm volatile("s_waitcnt vmcnt(0)" ::: "memory");
    }
    __builtin_amdgcn_sched_barrier(0);
    __builtin_amdgcn_s_barrier();      // tile t visible to all waves

    const f16* sA = sAB[t & 1][0];
    const f16* sB = sAB[t & 1][1];
#pragma unroll
    for (int ks = 0; ks < 2; ++ks) {
      h8 af[8], bf[4];
#pragma unroll
      for (int i = 0; i < 8; ++i) af[i] = fragld64(sA, wm + i * 16 + ln, ks * 4 + quad);
#pragma unroll
      for (int j = 0; j < 4; ++j) bf[j] = fragld64(sB, wn + j * 16 + ln, ks * 4 + quad);
      __builtin_amdgcn_s_setprio(1);
#pragma unroll
      for (int i = 0; i < 8; ++i)
#pragma unroll
        for (int j = 0; j < 4; ++j)
          acc[i][j] = __builtin_amdgcn_mfma_f32_16x16x32_f16(af[i], bf[j], acc[i][j], 0, 0, 0);
      __builtin_amdgcn_s_setprio(0);
    }
    __builtin_amdgcn_s_barrier();      // all reads of buf t done before overwrite
  }

  float bv[4];
#pragma unroll
  for (int j = 0; j < 4; ++j) bv[j] = bias[bn + wn + j * 16 + ln];
#pragma unroll
  for (int i = 0; i < 8; ++i)
#pragma unroll
    for (int j = 0; j < 4; ++j)
#pragma unroll
      for (int r = 0; r < 4; ++r) {
        const int row = bm + wm + i * 16 + quad * 4 + r;   // C: row=quad*4+reg
        const int col = bn + wn + j * 16 + ln;             //    col=lane&15
        const float val = acc[i][j][r] + bv[j];
        if (Ch) Ch[(size_t)row * N + col] = (f16)val;
        else    Cf[(size_t)row * N + col] = val;
      }
}

// ---------------------------------------------------------------------------
// rope_convert: fp16 qkv -> RoPE'd Qb/Kb, head-major [h][t][96] ZERO-PADDED
// (cols 80..95). Softmax scale folded into Qb. Vectorized (G13), 1 wave/token.
// ---------------------------------------------------------------------------
__global__ __launch_bounds__(256) void rope_convert(
    const f16* __restrict__ qkv, const float* __restrict__ cosb,
    const float* __restrict__ sinb, f16* __restrict__ Qb, f16* __restrict__ Kb) {
  const int tid = threadIdx.x;
  const int wave = tid >> 6, lane = tid & 63;
  const int t = blockIdx.x * 4 + wave;
  const size_t rowb = (size_t)t * N3_;
  const float qscale = 0.11180339887498949f;
#pragma unroll
  for (int u = 0; u < 5; ++u) {
    const int g = u * 64 + lane;          // chunk id 0..319 within token
    const int e = g * 8;                  // element 0..2552 (q then k)
    const int d = e % HD_;                // multiple of 8
    const int h = (e % D_HID) / HD_;
    const bool isK = e >= D_HID;
    const bool lo = d < 40;
    const int pe = lo ? e + 40 : e - 40;  // rotate_half partner chunk
    f16 v[8], p[8];
    *(int4*)v = *(const int4*)(qkv + rowb + e);
    *(int4*)p = *(const int4*)(qkv + rowb + pe);
    const float4 cs0 = *(const float4*)(cosb + (size_t)t * HD_ + d);
    const float4 cs1 = *(const float4*)(cosb + (size_t)t * HD_ + d + 4);
    const float4 sn0 = *(const float4*)(sinb + (size_t)t * HD_ + d);
    const float4 sn1 = *(const float4*)(sinb + (size_t)t * HD_ + d + 4);
    const float cs[8] = {cs0.x, cs0.y, cs0.z, cs0.w, cs1.x, cs1.y, cs1.z, cs1.w};
    const float sn[8] = {sn0.x, sn0.y, sn0.z, sn0.w, sn1.x, sn1.y, sn1.z, sn1.w};
    f16 o[8];
#pragma unroll
    for (int j = 0; j < 8; ++j) {
      const float pv = lo ? -(float)p[j] : (float)p[j];
      const float ov = (float)v[j] * cs[j] + pv * sn[j];
      o[j] = (f16)(isK ? ov : ov * qscale);
    }
    *(int4*)((isK ? Kb : Qb) + ((size_t)h * T_TOK + t) * QPAD + d) = *(const int4*)o;
  }
  // zero pad columns 80..95 (ws is poisoned): 64 lanes = 2(qk) x 16(h) x 2(half)
  {
    const int qk = lane >> 5, h = (lane >> 1) & 15, half = lane & 1;
    f16* dst = (qk ? Kb : Qb) + ((size_t)h * T_TOK + t) * QPAD + 80 + half * 8;
    *(int4*)dst = make_int4(0, 0, 0, 0);
  }
}

// ---------------------------------------------------------------------------
// vt_convert: v (fp16, cols 2560..3839 of qkv) -> Vt[h][d][t] (transposed).
// ---------------------------------------------------------------------------
__global__ __launch_bounds__(256) void vt_convert(const f16* __restrict__ qkv,
                                                  f16* __restrict__ Vt) {
  __shared__ f16 tl[HD_][136];
  const int h = blockIdx.x & 15;
  const int t0 = (blockIdx.x >> 4) * 128;
  const int tid = threadIdx.x;
#pragma unroll
  for (int it = 0; it < 5; ++it) {
    const int e = tid + it * 256;
    const int t = e / 10, pc = e % 10;
    int4 v = *(const int4*)(qkv + (size_t)(t0 + t) * N3_ + 2 * D_HID + h * HD_ + pc * 8);
    f16 tmp[8];
    *(int4*)tmp = v;
#pragma unroll
    for (int u = 0; u < 8; ++u) tl[pc * 8 + u][t] = tmp[u];
  }
  __syncthreads();
#pragma unroll
  for (int it = 0; it < 5; ++it) {
    const int e = tid + it * 256;
    const int d = e >> 4, pt = e & 15;
    *(int4*)(Vt + ((size_t)h * HD_ + d) * T_TOK + t0 + pt * 8) = *(const int4*)&tl[d][pt * 8];
  }
}

// ---------------------------------------------------------------------------
// attn_flash: BARRIER-FREE flash attention, T5 setprio (unchanged from R1).
// ---------------------------------------------------------------------------
__global__ __launch_bounds__(256, 2) void attn_flash(
    const f16* __restrict__ Qb, const f16* __restrict__ Kb,
    const f16* __restrict__ Vt, f16* __restrict__ Oa) {
  __shared__ f16 Ps[4][64][72];              // per-wave P tile, stride 72
  const int tid = threadIdx.x;
  const int wave = tid >> 6, lane = tid & 63;
  const int quad = lane >> 4, ln = lane & 15;
  const int h = blockIdx.x & 15;
  const int qb = (blockIdx.x >> 4) & 3;
  const int c = blockIdx.x >> 6;
  const int t0 = c * L_ + qb * 256 + wave * 64;
  const size_t hb = (size_t)h * T_TOK;

  h8 aq[4][3];
#pragma unroll
  for (int i = 0; i < 4; ++i)
#pragma unroll
    for (int ks = 0; ks < 3; ++ks)
      aq[i][ks] = *(const h8*)(Qb + (hb + t0 + i * 16 + ln) * QPAD + ks * 32 + quad * 8);

  f32x4 o[4][5];
  float lsum[4][4];
#pragma unroll
  for (int i = 0; i < 4; ++i) {
#pragma unroll
    for (int jn = 0; jn < 5; ++jn) o[i][jn] = (f32x4){0.f, 0.f, 0.f, 0.f};
#pragma unroll
    for (int r = 0; r < 4; ++r) lsum[i][r] = 0.f;
  }

  for (int kb = 0; kb < 16; ++kb) {
    const int kt0 = c * L_ + kb * 64;
#pragma unroll
    for (int j = 0; j < 4; ++j) {
      h8 bk[3];
#pragma unroll
      for (int ks = 0; ks < 3; ++ks)
        bk[ks] = *(const h8*)(Kb + (hb + kt0 + j * 16 + ln) * QPAD + ks * 32 + quad * 8);
      f32x4 s[4];
#pragma unroll
      for (int i = 0; i < 4; ++i) s[i] = (f32x4){0.f, 0.f, 0.f, 0.f};
      __builtin_amdgcn_s_setprio(1);
#pragma unroll
      for (int ks = 0; ks < 3; ++ks)
#pragma unroll
        for (int i = 0; i < 4; ++i)
          s[i] = __builtin_amdgcn_mfma_f32_16x16x32_f16(aq[i][ks], bk[ks], s[i], 0, 0, 0);
      __builtin_amdgcn_s_setprio(0);
#pragma unroll
      for (int i = 0; i < 4; ++i)
#pragma unroll
        for (int r = 0; r < 4; ++r) {
          const float p = __expf(s[i][r]);
          lsum[i][r] += p;
          Ps[wave][i * 16 + quad * 4 + r][j * 16 + ln] = (f16)p;
        }
    }
#pragma unroll
    for (int ks = 0; ks < 2; ++ks) {
      h8 ap[4];
#pragma unroll
      for (int i = 0; i < 4; ++i)
        ap[i] = *(const h8*)&Ps[wave][i * 16 + ln][ks * 32 + quad * 8];
#pragma unroll
      for (int jn = 0; jn < 5; ++jn) {
        const h8 bv = *(const h8*)(Vt + ((size_t)h * HD_ + jn * 16 + ln) * T_TOK
                                   + kt0 + ks * 32 + quad * 8);
        __builtin_amdgcn_s_setprio(1);
#pragma unroll
        for (int i = 0; i < 4; ++i)
          o[i][jn] = __builtin_amdgcn_mfma_f32_16x16x32_f16(ap[i], bv, o[i][jn], 0, 0, 0);
        __builtin_amdgcn_s_setprio(0);
      }
    }
  }

#pragma unroll
  for (int i = 0; i < 4; ++i)
#pragma unroll
    for (int r = 0; r < 4; ++r) {
      float s = lsum[i][r];
#pragma unroll
      for (int off = 1; off < 16; off <<= 1) s += __shfl_xor(s, off);
      lsum[i][r] = 1.f / s;
    }

#pragma unroll
  for (int i = 0; i < 4; ++i)
#pragma unroll
    for (int r = 0; r < 4; ++r) {
      const int t = t0 + i * 16 + quad * 4 + r;
      const float inv = lsum[i][r];
#pragma unroll
      for (int jn = 0; jn < 5; ++jn)
        Oa[(size_t)t * D_HID + h * HD_ + jn * 16 + ln] = (f16)(o[i][jn][r] * inv);
    }
}

// ---------------------------------------------------------------------------
extern "C" void kernel_launch(void* const* d_in, const int* in_sizes, int n_in,
                              void* d_out, int out_size, void* d_ws, size_t ws_size,
                              hipStream_t stream) {
  (void)in_sizes; (void)n_in; (void)out_size; (void)ws_size;
  const float* x      = (const float*)d_in[0];
  const float* cosb   = (const float*)d_in[1];
  const float* sinb   = (const float*)d_in[2];
  const float* w_qkv  = (const float*)d_in[3];
  const float* b_qkv  = (const float*)d_in[4];
  const float* w_proj = (const float*)d_in[5];
  const float* b_proj = (const float*)d_in[6];
  float* out = (float*)d_out;

  // workspace map (bytes):
  //  [0)           qkv f16    62,914,560  } aliased by attn O (21 MB) post-vt
  //  [62914560)    Qb [16][8192][96]  25,165,824
  //  [88080384)    Kb [16][8192][96]  25,165,824
  //  [113246208)   Vt [16][80][8192]  20,971,520
  //  [134217728)   Wqkv_t              9,830,400
  //  [144048128)   Wproj_t             3,276,800   -> end 147,324,928
  char* ws = (char*)d_ws;
  f16* qkv_h  = (f16*)(ws);
  f16* attn_h = (f16*)(ws);                          // alias (post-attention)
  f16* x_h    = (f16*)(ws + 62914560);               // temp in Qb slot
  f16* Qb     = (f16*)(ws + 62914560);               // alias (post-GEMM1)
  f16* Kb     = (f16*)(ws + 88080384);
  f16* Vt     = (f16*)(ws + 113246208);
  f16* wq_t   = (f16*)(ws + 134217728);
  f16* wp_t   = (f16*)(ws + 144048128);

  // 1) fp16 conversions (X, W^T)
  convert_x<<<(T_TOK * D_HID / 4) / 256, 256, 0, stream>>>(x, x_h);
  convert_w_t<<<dim3(N3_ / 32, D_HID / 32), 256, 0, stream>>>(w_qkv, wq_t, D_HID, N3_);
  convert_w_t<<<dim3(D_HID / 32, D_HID / 32), 256, 0, stream>>>(w_proj, wp_t, D_HID, D_HID);
  // 2) qkv = x @ w_qkv + b_qkv  (fp16 out): 256x256 tiles, 1D grid (480 blocks)
  gemm_f16<<<(N3_ / 256) * (T_TOK / 256), 512, 0, stream>>>(
      x_h, wq_t, b_qkv, nullptr, qkv_h, T_TOK, N3_, D_HID);
  // 3) RoPE + head-major padded fp16 Q/K (scale folded into Q), 1 wave/token
  rope_convert<<<T_TOK / 4, 256, 0, stream>>>(qkv_h, cosb, sinb, Qb, Kb);
  // 4) V transpose to [h][d][t]
  vt_convert<<<H_ * (T_TOK / 128), 256, 0, stream>>>(qkv_h, Vt);
  // 5) barrier-free flash attention -> attn fp16 [t][1280]
  attn_flash<<<C_ * 4 * H_, 256, 0, stream>>>(Qb, Kb, Vt, attn_h);
  // 6) out = attn @ w_proj + b_proj  (fp32 out): 160 blocks
  gemm_f16<<<(D_HID / 256) * (T_TOK / 256), 512, 0, stream>>>(
      attn_h, wp_t, b_proj, out, nullptr, T_TOK, D_HID, D_HID);
}

// Round 3
// 370.003 us; speedup vs baseline: 1.0167x; 1.0157x over previous
//
#include <hip/hip_runtime.h>

// Problem constants (fixed by setup_inputs)
#define T_TOK 8192
#define D_HID 1280
#define H_    16
#define HD_   80
#define C_    8
#define L_    1024
#define N3_   3840
#define QPAD  96     // Q/K head-dim padded to 96 (3 x K=32 MFMA steps)

typedef _Float16 f16;
typedef __attribute__((ext_vector_type(8))) _Float16 h8;   // MFMA A/B frag (4 VGPR)
typedef __attribute__((ext_vector_type(4))) float f32x4;   // MFMA C/D frag

// ---------------------------------------------------------------------------
// convert_x: fp32 -> fp16, same layout. 4 elems/thread.
// ---------------------------------------------------------------------------
__global__ __launch_bounds__(256) void convert_x(const float* __restrict__ x,
                                                 f16* __restrict__ y) {
  const int g = blockIdx.x * 256 + threadIdx.x;
  const float4 v = ((const float4*)x)[g];
  f16 o[4] = {(f16)v.x, (f16)v.y, (f16)v.z, (f16)v.w};
  ((uint2*)y)[g] = *(const uint2*)o;
}

// ---------------------------------------------------------------------------
// convert_w_t: W[K][N] fp32 -> Wt[N][K] fp16 (transposed for B^T GEMM).
// ---------------------------------------------------------------------------
__global__ __launch_bounds__(256) void convert_w_t(const float* __restrict__ W,
                                                   f16* __restrict__ Wt,
                                                   int K, int N) {
  __shared__ float tile[32][33];
  const int n0 = blockIdx.x * 32, k0 = blockIdx.y * 32;
  const int c = threadIdx.x & 31, r0 = threadIdx.x >> 5;
#pragma unroll
  for (int it = 0; it < 4; ++it) {
    const int r = r0 + it * 8;
    tile[r][c] = W[(size_t)(k0 + r) * N + n0 + c];
  }
  __syncthreads();
#pragma unroll
  for (int it = 0; it < 4; ++it) {
    const int r = r0 + it * 8;
    Wt[(size_t)(n0 + r) * K + k0 + c] = (f16)tile[c][r];
  }
}

// ---------------------------------------------------------------------------
// gemm_f16: C = A @ B^T + bias, fp16 in, fp32 MFMA accumulate.
// R3: true 4-phase-per-tile interleave (T3/T4 from m201 template):
//   per K-tile (BK=64), 4 phases, each = {ds_read new frags | stage one
//   half-tile | s_barrier | setprio(1) 16 MFMA setprio(0) | s_barrier}.
//   Quadrants: p0=(i0-3,j0-1) p1=(i0-3,j2-3) p2=(i4-7,j2-3) p3=(i4-7,j0-1),
//   bf01 held in regs so p3 is reg-only (A halves of T+2 stage safely there).
//   Staging stream: p0->T+1.B0, p1->T+1.B1, p3->T+2.A0+A1.
//   Tile-boundary gate: vmcnt(4) counted (== T+2.A still in flight), never 0
//   in steady state. XOR swizzle unchanged (0 conflicts measured).
// ---------------------------------------------------------------------------
__device__ __forceinline__ void stage_half(const f16* __restrict__ gpanel, int K,
                                           f16* sdst, int t, int half) {
  // half-tile = 128 rows x 64 cols f16 = 1024 x 16B chunks; 512 thr -> 2 each
#pragma unroll
  for (int r = 0; r < 2; ++r) {
    const int s = r * 512 + (int)threadIdx.x;         // 0..1023
    const int row = half * 128 + (s >> 3);
    const int part = (s & 7) ^ (row & 7);             // XOR swizzle (src side)
    const f16* gp = gpanel + (size_t)row * K + t * 64 + part * 8;
    __builtin_amdgcn_global_load_lds(
        (const __attribute__((address_space(1))) void*)gp,
        (__attribute__((address_space(3))) void*)(sdst + row * 64 + (s & 7) * 8),
        16, 0, 0);
  }
}

__device__ __forceinline__ h8 fragld64(const f16* s, int row, int c) {
  const int slot = c ^ (row & 7);                     // c = ks*4 + quad
  return *(const h8*)&s[row * 64 + slot * 8];
}

__global__ __launch_bounds__(512, 2) void gemm_f16(
    const f16* __restrict__ A, const f16* __restrict__ B,
    const float* __restrict__ bias,
    float* __restrict__ Cf, f16* __restrict__ Ch,
    int M, int N, int K) {
  __shared__ f16 sAB[2][2][256 * 64];                 // 128 KiB, dbuf x {A,B}
  const int tid = threadIdx.x;
  const int wave = tid >> 6, lane = tid & 63;
  const int quad = lane >> 4, ln = lane & 15;

  // XCD-chunked bijective swizzle (nwg % 8 == 0: 480 / 160)
  const int nwg = gridDim.x;
  int wg = blockIdx.x;
  wg = (wg & 7) * (nwg >> 3) + (wg >> 3);
  const int nbx = N >> 8;
  const int bm = (wg / nbx) * 256, bn = (wg % nbx) * 256;
  const int wm = (wave >> 2) * 128, wn = (wave & 3) * 64;

  f32x4 acc[8][4];
#pragma unroll
  for (int i = 0; i < 8; ++i)
#pragma unroll
    for (int j = 0; j < 4; ++j) acc[i][j] = (f32x4){0.f, 0.f, 0.f, 0.f};

  const f16* Abase = A + (size_t)bm * K;
  const f16* Bbase = B + (size_t)bn * K;
  const int nt = K >> 6;                               // 20

  // prologue: T0.{A0,A1,B0,B1} + T1.{A0,A1}  (12 loads/thread)
  stage_half(Abase, K, sAB[0][0], 0, 0);
  stage_half(Abase, K, sAB[0][0], 0, 1);
  stage_half(Bbase, K, sAB[0][1], 0, 0);
  stage_half(Bbase, K, sAB[0][1], 0, 1);
  stage_half(Abase, K, sAB[1][0], 1, 0);
  stage_half(Abase, K, sAB[1][0], 1, 1);
  asm volatile("s_waitcnt vmcnt(4)" ::: "memory");     // T0 landed, T1.A in flight
  __builtin_amdgcn_sched_barrier(0);
  __builtin_amdgcn_s_barrier();

  for (int t = 0; t < nt; ++t) {
    const f16* sA = sAB[t & 1][0];
    const f16* sB = sAB[t & 1][1];
    const int nb = (t + 1) & 1;
    h8 af[4][2], bf01[2][2], bf23[2][2];

    // ---- phase 0: read af(i0-3)+bf(j0-1); stage T+1.B0; MFMA q(0-3,0-1)
#pragma unroll
    for (int i = 0; i < 4; ++i)
#pragma unroll
      for (int ks = 0; ks < 2; ++ks)
        af[i][ks] = fragld64(sA, wm + i * 16 + ln, ks * 4 + quad);
#pragma unroll
    for (int j = 0; j < 2; ++j)
#pragma unroll
      for (int ks = 0; ks < 2; ++ks)
        bf01[j][ks] = fragld64(sB, wn + j * 16 + ln, ks * 4 + quad);
    if (t + 1 < nt) stage_half(Bbase, K, sAB[nb][1], t + 1, 0);
    __builtin_amdgcn_s_barrier();
    __builtin_amdgcn_s_setprio(1);
#pragma unroll
    for (int ks = 0; ks < 2; ++ks)
#pragma unroll
      for (int i = 0; i < 4; ++i)
#pragma unroll
        for (int j = 0; j < 2; ++j)
          acc[i][j] = __builtin_amdgcn_mfma_f32_16x16x32_f16(af[i][ks], bf01[j][ks], acc[i][j], 0, 0, 0);
    __builtin_amdgcn_s_setprio(0);
    __builtin_amdgcn_s_barrier();

    // ---- phase 1: read bf(j2-3); stage T+1.B1; MFMA q(0-3,2-3)
#pragma unroll
    for (int j = 0; j < 2; ++j)
#pragma unroll
      for (int ks = 0; ks < 2; ++ks)
        bf23[j][ks] = fragld64(sB, wn + (j + 2) * 16 + ln, ks * 4 + quad);
    if (t + 1 < nt) stage_half(Bbase, K, sAB[nb][1], t + 1, 1);
    __builtin_amdgcn_s_barrier();
    __builtin_amdgcn_s_setprio(1);
#pragma unroll
    for (int ks = 0; ks < 2; ++ks)
#pragma unroll
      for (int i = 0; i < 4; ++i)
#pragma unroll
        for (int j = 0; j < 2; ++j)
          acc[i][j + 2] = __builtin_amdgcn_mfma_f32_16x16x32_f16(af[i][ks], bf23[j][ks], acc[i][j + 2], 0, 0, 0);
    __builtin_amdgcn_s_setprio(0);
    __builtin_amdgcn_s_barrier();

    // ---- phase 2: read af(i4-7); MFMA q(4-7,2-3)   (last reads of sA)
#pragma unroll
    for (int i = 0; i < 4; ++i)
#pragma unroll
      for (int ks = 0; ks < 2; ++ks)
        af[i][ks] = fragld64(sA, wm + (i + 4) * 16 + ln, ks * 4 + quad);
    __builtin_amdgcn_s_barrier();
    __builtin_amdgcn_s_setprio(1);
#pragma unroll
    for (int ks = 0; ks < 2; ++ks)
#pragma unroll
      for (int i = 0; i < 4; ++i)
#pragma unroll
        for (int j = 0; j < 2; ++j)
          acc[i + 4][j + 2] = __builtin_amdgcn_mfma_f32_16x16x32_f16(af[i][ks], bf23[j][ks], acc[i + 4][j + 2], 0, 0, 0);
    __builtin_amdgcn_s_setprio(0);
    __builtin_amdgcn_s_barrier();                      // closes all sA reads

    // ---- phase 3: stage T+2.A0,A1 (into sA: safe, reads closed);
    //               MFMA q(4-7,0-1) reg-only; counted gate for next tile.
    if (t + 2 < nt) {
      stage_half(Abase, K, sAB[t & 1][0], t + 2, 0);
      stage_half(Abase, K, sAB[t & 1][0], t + 2, 1);
    }
    __builtin_amdgcn_s_setprio(1);
#pragma unroll
    for (int ks = 0; ks < 2; ++ks)
#pragma unroll
      for (int i = 0; i < 4; ++i)
#pragma unroll
        for (int j = 0; j < 2; ++j)
          acc[i + 4][j] = __builtin_amdgcn_mfma_f32_16x16x32_f16(af[i][ks], bf01[j][ks], acc[i + 4][j], 0, 0, 0);
    __builtin_amdgcn_s_setprio(0);
    if (t + 1 < nt) {
      if (t + 2 < nt) asm volatile("s_waitcnt vmcnt(4)" ::: "memory");
      else            asm volatile("s_waitcnt vmcnt(0)" ::: "memory");
      __builtin_amdgcn_sched_barrier(0);
      __builtin_amdgcn_s_barrier();                    // next tile fully staged
    }
  }

  float bv[4];
#pragma unroll
  for (int j = 0; j < 4; ++j) bv[j] = bias[bn + wn + j * 16 + ln];
#pragma unroll
  for (int i = 0; i < 8; ++i)
#pragma unroll
    for (int j = 0; j < 4; ++j)
#pragma unroll
      for (int r = 0; r < 4; ++r) {
        const int row = bm + wm + i * 16 + quad * 4 + r;   // C: row=quad*4+reg
        const int col = bn + wn + j * 16 + ln;             //    col=lane&15
        const float val = acc[i][j][r] + bv[j];
        if (Ch) Ch[(size_t)row * N + col] = (f16)val;
        else    Cf[(size_t)row * N + col] = val;
      }
}

// ---------------------------------------------------------------------------
// rope_convert: fp16 qkv -> RoPE'd Qb/Kb, head-major [h][t][96] ZERO-PADDED
// (cols 80..95). Softmax scale folded into Qb. Vectorized (G13), 1 wave/token.
// ---------------------------------------------------------------------------
__global__ __launch_bounds__(256) void rope_convert(
    const f16* __restrict__ qkv, const float* __restrict__ cosb,
    const float* __restrict__ sinb, f16* __restrict__ Qb, f16* __restrict__ Kb) {
  const int tid = threadIdx.x;
  const int wave = tid >> 6, lane = tid & 63;
  const int t = blockIdx.x * 4 + wave;
  const size_t rowb = (size_t)t * N3_;
  const float qscale = 0.11180339887498949f;
#pragma unroll
  for (int u = 0; u < 5; ++u) {
    const int g = u * 64 + lane;          // chunk id 0..319 within token
    const int e = g * 8;                  // element 0..2552 (q then k)
    const int d = e % HD_;                // multiple of 8
    const int h = (e % D_HID) / HD_;
    const bool isK = e >= D_HID;
    const bool lo = d < 40;
    const int pe = lo ? e + 40 : e - 40;  // rotate_half partner chunk
    f16 v[8], p[8];
    *(int4*)v = *(const int4*)(qkv + rowb + e);
    *(int4*)p = *(const int4*)(qkv + rowb + pe);
    const float4 cs0 = *(const float4*)(cosb + (size_t)t * HD_ + d);
    const float4 cs1 = *(const float4*)(cosb + (size_t)t * HD_ + d + 4);
    const float4 sn0 = *(const float4*)(sinb + (size_t)t * HD_ + d);
    const float4 sn1 = *(const float4*)(sinb + (size_t)t * HD_ + d + 4);
    const float cs[8] = {cs0.x, cs0.y, cs0.z, cs0.w, cs1.x, cs1.y, cs1.z, cs1.w};
    const float sn[8] = {sn0.x, sn0.y, sn0.z, sn0.w, sn1.x, sn1.y, sn1.z, sn1.w};
    f16 o[8];
#pragma unroll
    for (int j = 0; j < 8; ++j) {
      const float pv = lo ? -(float)p[j] : (float)p[j];
      const float ov = (float)v[j] * cs[j] + pv * sn[j];
      o[j] = (f16)(isK ? ov : ov * qscale);
    }
    *(int4*)((isK ? Kb : Qb) + ((size_t)h * T_TOK + t) * QPAD + d) = *(const int4*)o;
  }
  // zero pad columns 80..95 (ws is poisoned): 64 lanes = 2(qk) x 16(h) x 2(half)
  {
    const int qk = lane >> 5, h = (lane >> 1) & 15, half = lane & 1;
    f16* dst = (qk ? Kb : Qb) + ((size_t)h * T_TOK + t) * QPAD + 80 + half * 8;
    *(int4*)dst = make_int4(0, 0, 0, 0);
  }
}

// ---------------------------------------------------------------------------
// vt_convert: v (fp16, cols 2560..3839 of qkv) -> Vt[h][d][t] (transposed).
// ---------------------------------------------------------------------------
__global__ __launch_bounds__(256) void vt_convert(const f16* __restrict__ qkv,
                                                  f16* __restrict__ Vt) {
  __shared__ f16 tl[HD_][136];
  const int h = blockIdx.x & 15;
  const int t0 = (blockIdx.x >> 4) * 128;
  const int tid = threadIdx.x;
#pragma unroll
  for (int it = 0; it < 5; ++it) {
    const int e = tid + it * 256;
    const int t = e / 10, pc = e % 10;
    int4 v = *(const int4*)(qkv + (size_t)(t0 + t) * N3_ + 2 * D_HID + h * HD_ + pc * 8);
    f16 tmp[8];
    *(int4*)tmp = v;
#pragma unroll
    for (int u = 0; u < 8; ++u) tl[pc * 8 + u][t] = tmp[u];
  }
  __syncthreads();
#pragma unroll
  for (int it = 0; it < 5; ++it) {
    const int e = tid + it * 256;
    const int d = e >> 4, pt = e & 15;
    *(int4*)(Vt + ((size_t)h * HD_ + d) * T_TOK + t0 + pt * 8) = *(const int4*)&tl[d][pt * 8];
  }
}

// ---------------------------------------------------------------------------
// attn_flash: BARRIER-FREE flash attention, T5 setprio (unchanged).
// ---------------------------------------------------------------------------
__global__ __launch_bounds__(256, 2) void attn_flash(
    const f16* __restrict__ Qb, const f16* __restrict__ Kb,
    const f16* __restrict__ Vt, f16* __restrict__ Oa) {
  __shared__ f16 Ps[4][64][72];              // per-wave P tile, stride 72
  const int tid = threadIdx.x;
  const int wave = tid >> 6, lane = tid & 63;
  const int quad = lane >> 4, ln = lane & 15;
  const int h = blockIdx.x & 15;
  const int qb = (blockIdx.x >> 4) & 3;
  const int c = blockIdx.x >> 6;
  const int t0 = c * L_ + qb * 256 + wave * 64;
  const size_t hb = (size_t)h * T_TOK;

  h8 aq[4][3];
#pragma unroll
  for (int i = 0; i < 4; ++i)
#pragma unroll
    for (int ks = 0; ks < 3; ++ks)
      aq[i][ks] = *(const h8*)(Qb + (hb + t0 + i * 16 + ln) * QPAD + ks * 32 + quad * 8);

  f32x4 o[4][5];
  float lsum[4][4];
#pragma unroll
  for (int i = 0; i < 4; ++i) {
#pragma unroll
    for (int jn = 0; jn < 5; ++jn) o[i][jn] = (f32x4){0.f, 0.f, 0.f, 0.f};
#pragma unroll
    for (int r = 0; r < 4; ++r) lsum[i][r] = 0.f;
  }

  for (int kb = 0; kb < 16; ++kb) {
    const int kt0 = c * L_ + kb * 64;
#pragma unroll
    for (int j = 0; j < 4; ++j) {
      h8 bk[3];
#pragma unroll
      for (int ks = 0; ks < 3; ++ks)
        bk[ks] = *(const h8*)(Kb + (hb + kt0 + j * 16 + ln) * QPAD + ks * 32 + quad * 8);
      f32x4 s[4];
#pragma unroll
      for (int i = 0; i < 4; ++i) s[i] = (f32x4){0.f, 0.f, 0.f, 0.f};
      __builtin_amdgcn_s_setprio(1);
#pragma unroll
      for (int ks = 0; ks < 3; ++ks)
#pragma unroll
        for (int i = 0; i < 4; ++i)
          s[i] = __builtin_amdgcn_mfma_f32_16x16x32_f16(aq[i][ks], bk[ks], s[i], 0, 0, 0);
      __builtin_amdgcn_s_setprio(0);
#pragma unroll
      for (int i = 0; i < 4; ++i)
#pragma unroll
        for (int r = 0; r < 4; ++r) {
          const float p = __expf(s[i][r]);
          lsum[i][r] += p;
          Ps[wave][i * 16 + quad * 4 + r][j * 16 + ln] = (f16)p;
        }
    }
#pragma unroll
    for (int ks = 0; ks < 2; ++ks) {
      h8 ap[4];
#pragma unroll
      for (int i = 0; i < 4; ++i)
        ap[i] = *(const h8*)&Ps[wave][i * 16 + ln][ks * 32 + quad * 8];
#pragma unroll
      for (int jn = 0; jn < 5; ++jn) {
        const h8 bv = *(const h8*)(Vt + ((size_t)h * HD_ + jn * 16 + ln) * T_TOK
                                   + kt0 + ks * 32 + quad * 8);
        __builtin_amdgcn_s_setprio(1);
#pragma unroll
        for (int i = 0; i < 4; ++i)
          o[i][jn] = __builtin_amdgcn_mfma_f32_16x16x32_f16(ap[i], bv, o[i][jn], 0, 0, 0);
        __builtin_amdgcn_s_setprio(0);
      }
    }
  }

#pragma unroll
  for (int i = 0; i < 4; ++i)
#pragma unroll
    for (int r = 0; r < 4; ++r) {
      float s = lsum[i][r];
#pragma unroll
      for (int off = 1; off < 16; off <<= 1) s += __shfl_xor(s, off);
      lsum[i][r] = 1.f / s;
    }

#pragma unroll
  for (int i = 0; i < 4; ++i)
#pragma unroll
    for (int r = 0; r < 4; ++r) {
      const int t = t0 + i * 16 + quad * 4 + r;
      const float inv = lsum[i][r];
#pragma unroll
      for (int jn = 0; jn < 5; ++jn)
        Oa[(size_t)t * D_HID + h * HD_ + jn * 16 + ln] = (f16)(o[i][jn][r] * inv);
    }
}

// ---------------------------------------------------------------------------
extern "C" void kernel_launch(void* const* d_in, const int* in_sizes, int n_in,
                              void* d_out, int out_size, void* d_ws, size_t ws_size,
                              hipStream_t stream) {
  (void)in_sizes; (void)n_in; (void)out_size; (void)ws_size;
  const float* x      = (const float*)d_in[0];
  const float* cosb   = (const float*)d_in[1];
  const float* sinb   = (const float*)d_in[2];
  const float* w_qkv  = (const float*)d_in[3];
  const float* b_qkv  = (const float*)d_in[4];
  const float* w_proj = (const float*)d_in[5];
  const float* b_proj = (const float*)d_in[6];
  float* out = (float*)d_out;

  // workspace map (bytes):
  //  [0)           qkv f16    62,914,560  } aliased by attn O (21 MB) post-vt
  //  [62914560)    Qb [16][8192][96]  25,165,824
  //  [88080384)    Kb [16][8192][96]  25,165,824
  //  [113246208)   Vt [16][80][8192]  20,971,520
  //  [134217728)   Wqkv_t              9,830,400
  //  [144048128)   Wproj_t             3,276,800   -> end 147,324,928
  char* ws = (char*)d_ws;
  f16* qkv_h  = (f16*)(ws);
  f16* attn_h = (f16*)(ws);                          // alias (post-attention)
  f16* x_h    = (f16*)(ws + 62914560);               // temp in Qb slot
  f16* Qb     = (f16*)(ws + 62914560);               // alias (post-GEMM1)
  f16* Kb     = (f16*)(ws + 88080384);
  f16* Vt     = (f16*)(ws + 113246208);
  f16* wq_t   = (f16*)(ws + 134217728);
  f16* wp_t   = (f16*)(ws + 144048128);

  // 1) fp16 conversions (X, W^T)
  convert_x<<<(T_TOK * D_HID / 4) / 256, 256, 0, stream>>>(x, x_h);
  convert_w_t<<<dim3(N3_ / 32, D_HID / 32), 256, 0, stream>>>(w_qkv, wq_t, D_HID, N3_);
  convert_w_t<<<dim3(D_HID / 32, D_HID / 32), 256, 0, stream>>>(w_proj, wp_t, D_HID, D_HID);
  // 2) qkv = x @ w_qkv + b_qkv  (fp16 out): 256x256 tiles, 480 blocks
  gemm_f16<<<(N3_ / 256) * (T_TOK / 256), 512, 0, stream>>>(
      x_h, wq_t, b_qkv, nullptr, qkv_h, T_TOK, N3_, D_HID);
  // 3) RoPE + head-major padded fp16 Q/K (scale folded into Q), 1 wave/token
  rope_convert<<<T_TOK / 4, 256, 0, stream>>>(qkv_h, cosb, sinb, Qb, Kb);
  // 4) V transpose to [h][d][t]
  vt_convert<<<H_ * (T_TOK / 128), 256, 0, stream>>>(qkv_h, Vt);
  // 5) barrier-free flash attention -> attn fp16 [t][1280]
  attn_flash<<<C_ * 4 * H_, 256, 0, stream>>>(Qb, Kb, Vt, attn_h);
  // 6) out = attn @ w_proj + b_proj  (fp32 out): 160 blocks
  gemm_f16<<<(D_HID / 256) * (T_TOK / 256), 512, 0, stream>>>(
      attn_h, wp_t, b_proj, out, nullptr, T_TOK, D_HID, D_HID);
}

// Round 4
// 359.517 us; speedup vs baseline: 1.0464x; 1.0292x over previous
//
#include <hip/hip_runtime.h>

// Problem constants (fixed by setup_inputs)
#define T_TOK 8192
#define D_HID 1280
#define H_    16
#define HD_   80
#define C_    8
#define L_    1024
#define N3_   3840
#define QPAD  96     // Q/K head-dim padded to 96 (3 x K=32 MFMA steps)

typedef _Float16 f16;
typedef __attribute__((ext_vector_type(8))) _Float16 h8;   // MFMA A/B frag (4 VGPR)
typedef __attribute__((ext_vector_type(4))) float f32x4;   // MFMA C/D frag

// ---------------------------------------------------------------------------
// convert_x: fp32 -> fp16, same layout. 4 elems/thread.
// ---------------------------------------------------------------------------
__global__ __launch_bounds__(256) void convert_x(const float* __restrict__ x,
                                                 f16* __restrict__ y) {
  const int g = blockIdx.x * 256 + threadIdx.x;
  const float4 v = ((const float4*)x)[g];
  f16 o[4] = {(f16)v.x, (f16)v.y, (f16)v.z, (f16)v.w};
  ((uint2*)y)[g] = *(const uint2*)o;
}

// ---------------------------------------------------------------------------
// convert_w_t: W[K][N] fp32 -> Wt[N][K] fp16 (transposed for B^T GEMM).
// ---------------------------------------------------------------------------
__global__ __launch_bounds__(256) void convert_w_t(const float* __restrict__ W,
                                                   f16* __restrict__ Wt,
                                                   int K, int N) {
  __shared__ float tile[32][33];
  const int n0 = blockIdx.x * 32, k0 = blockIdx.y * 32;
  const int c = threadIdx.x & 31, r0 = threadIdx.x >> 5;
#pragma unroll
  for (int it = 0; it < 4; ++it) {
    const int r = r0 + it * 8;
    tile[r][c] = W[(size_t)(k0 + r) * N + n0 + c];
  }
  __syncthreads();
#pragma unroll
  for (int it = 0; it < 4; ++it) {
    const int r = r0 + it * 8;
    Wt[(size_t)(n0 + r) * K + k0 + c] = (f16)tile[c][r];
  }
}

// ---------------------------------------------------------------------------
// gemm_f16: C = A @ B^T + bias, fp16 in, fp32 MFMA accumulate.
// R4: cluster-pipelined K-loop. Theory: per K-tile per CU, LDS drain
// (~2300 cyc) ~= MFMA (~2480 cyc); R3's read->barrier->MFMA phases
// serialized them (35% MfmaUtil = 620/1200 per phase, matched). Fix:
// issue cluster c+1's ds_reads BEFORE MFMA c (reg double-buffer) and
// drop to 2 barriers/tile (barriers only guard staging-vs-read hazards):
//   issue Q0+Q1 reads | stage T+1.B0 | MFMA Q0 | issue Q2 reads |
//   stage T+1.B1 | MFMA Q1 | lgkm(0)+barrier (sA reads closed) |
//   stage T+2.A -> sA | MFMA Q2,Q3 (reg-only, covers staging) |
//   vmcnt(4) + barrier (T+1 fully staged, T+2.A in flight).
// Quadrants: Q0=(i0-3,j0-1) Q1=(i0-3,j2-3) Q2=(i4-7,j2-3) Q3=(i4-7,j0-1).
// XOR swizzle unchanged (0 conflicts measured).
// ---------------------------------------------------------------------------
__device__ __forceinline__ void stage_half(const f16* __restrict__ gpanel, int K,
                                           f16* sdst, int t, int half) {
  // half-tile = 128 rows x 64 cols f16 = 1024 x 16B chunks; 512 thr -> 2 each
#pragma unroll
  for (int r = 0; r < 2; ++r) {
    const int s = r * 512 + (int)threadIdx.x;         // 0..1023
    const int row = half * 128 + (s >> 3);
    const int part = (s & 7) ^ (row & 7);             // XOR swizzle (src side)
    const f16* gp = gpanel + (size_t)row * K + t * 64 + part * 8;
    __builtin_amdgcn_global_load_lds(
        (const __attribute__((address_space(1))) void*)gp,
        (__attribute__((address_space(3))) void*)(sdst + row * 64 + (s & 7) * 8),
        16, 0, 0);
  }
}

__device__ __forceinline__ h8 fragld64(const f16* s, int row, int c) {
  const int slot = c ^ (row & 7);                     // c = ks*4 + quad
  return *(const h8*)&s[row * 64 + slot * 8];
}

__global__ __launch_bounds__(512, 2) void gemm_f16(
    const f16* __restrict__ A, const f16* __restrict__ B,
    const float* __restrict__ bias,
    float* __restrict__ Cf, f16* __restrict__ Ch,
    int M, int N, int K) {
  __shared__ f16 sAB[2][2][256 * 64];                 // 128 KiB, dbuf x {A,B}
  const int tid = threadIdx.x;
  const int wave = tid >> 6, lane = tid & 63;
  const int quad = lane >> 4, ln = lane & 15;

  // XCD-chunked bijective swizzle (nwg % 8 == 0: 480 / 160)
  const int nwg = gridDim.x;
  int wg = blockIdx.x;
  wg = (wg & 7) * (nwg >> 3) + (wg >> 3);
  const int nbx = N >> 8;
  const int bm = (wg / nbx) * 256, bn = (wg % nbx) * 256;
  const int wm = (wave >> 2) * 128, wn = (wave & 3) * 64;

  f32x4 acc[8][4];
#pragma unroll
  for (int i = 0; i < 8; ++i)
#pragma unroll
    for (int j = 0; j < 4; ++j) acc[i][j] = (f32x4){0.f, 0.f, 0.f, 0.f};

  const f16* Abase = A + (size_t)bm * K;
  const f16* Bbase = B + (size_t)bn * K;
  const int nt = K >> 6;                               // 20

  // prologue: T0.{A,B} + T1.A  (12 loads/thread)
  stage_half(Abase, K, sAB[0][0], 0, 0);
  stage_half(Abase, K, sAB[0][0], 0, 1);
  stage_half(Bbase, K, sAB[0][1], 0, 0);
  stage_half(Bbase, K, sAB[0][1], 0, 1);
  stage_half(Abase, K, sAB[1][0], 1, 0);
  stage_half(Abase, K, sAB[1][0], 1, 1);
  asm volatile("s_waitcnt vmcnt(4)" ::: "memory");     // T0 landed, T1.A in flight
  __builtin_amdgcn_sched_barrier(0);
  __builtin_amdgcn_s_barrier();

  for (int t = 0; t < nt; ++t) {
    const f16* sA = sAB[t & 1][0];
    const f16* sB = sAB[t & 1][1];
    const int nb = (t + 1) & 1;
    h8 af[4][2], af2[4][2], bf01[2][2], bf23[2][2];

    // issue reads for Q0 (af0-3, bf01) AND Q1 (bf23); stage T+1.B0
#pragma unroll
    for (int i = 0; i < 4; ++i)
#pragma unroll
      for (int ks = 0; ks < 2; ++ks)
        af[i][ks] = fragld64(sA, wm + i * 16 + ln, ks * 4 + quad);
#pragma unroll
    for (int j = 0; j < 2; ++j)
#pragma unroll
      for (int ks = 0; ks < 2; ++ks)
        bf01[j][ks] = fragld64(sB, wn + j * 16 + ln, ks * 4 + quad);
#pragma unroll
    for (int j = 0; j < 2; ++j)
#pragma unroll
      for (int ks = 0; ks < 2; ++ks)
        bf23[j][ks] = fragld64(sB, wn + (j + 2) * 16 + ln, ks * 4 + quad);
    if (t + 1 < nt) stage_half(Bbase, K, sAB[nb][1], t + 1, 0);

    // MFMA Q0 (compiler's counted lgkm wait covers af/bf01 only; bf23 drains under)
    __builtin_amdgcn_s_setprio(1);
#pragma unroll
    for (int ks = 0; ks < 2; ++ks)
#pragma unroll
      for (int i = 0; i < 4; ++i)
#pragma unroll
        for (int j = 0; j < 2; ++j)
          acc[i][j] = __builtin_amdgcn_mfma_f32_16x16x32_f16(af[i][ks], bf01[j][ks], acc[i][j], 0, 0, 0);
    __builtin_amdgcn_s_setprio(0);

    // issue Q2 reads (af4-7); stage T+1.B1
#pragma unroll
    for (int i = 0; i < 4; ++i)
#pragma unroll
      for (int ks = 0; ks < 2; ++ks)
        af2[i][ks] = fragld64(sA, wm + (i + 4) * 16 + ln, ks * 4 + quad);
    if (t + 1 < nt) stage_half(Bbase, K, sAB[nb][1], t + 1, 1);

    // MFMA Q1 (af x bf23); af4-7 reads drain underneath
    __builtin_amdgcn_s_setprio(1);
#pragma unroll
    for (int ks = 0; ks < 2; ++ks)
#pragma unroll
      for (int i = 0; i < 4; ++i)
#pragma unroll
        for (int j = 0; j < 2; ++j)
          acc[i][j + 2] = __builtin_amdgcn_mfma_f32_16x16x32_f16(af[i][ks], bf23[j][ks], acc[i][j + 2], 0, 0, 0);
    __builtin_amdgcn_s_setprio(0);

    // close ALL this-wave LDS reads, then barrier -> safe to overwrite sA
    asm volatile("s_waitcnt lgkmcnt(0)" ::: "memory");
    __builtin_amdgcn_sched_barrier(0);
    __builtin_amdgcn_s_barrier();
    if (t + 2 < nt) {
      stage_half(Abase, K, sAB[t & 1][0], t + 2, 0);
      stage_half(Abase, K, sAB[t & 1][0], t + 2, 1);
    }

    // MFMA Q2 + Q3: 32 reg-only MFMAs cover staging issue + barrier skew
    __builtin_amdgcn_s_setprio(1);
#pragma unroll
    for (int ks = 0; ks < 2; ++ks)
#pragma unroll
      for (int i = 0; i < 4; ++i)
#pragma unroll
        for (int j = 0; j < 2; ++j)
          acc[i + 4][j + 2] = __builtin_amdgcn_mfma_f32_16x16x32_f16(af2[i][ks], bf23[j][ks], acc[i + 4][j + 2], 0, 0, 0);
#pragma unroll
    for (int ks = 0; ks < 2; ++ks)
#pragma unroll
      for (int i = 0; i < 4; ++i)
#pragma unroll
        for (int j = 0; j < 2; ++j)
          acc[i + 4][j] = __builtin_amdgcn_mfma_f32_16x16x32_f16(af2[i][ks], bf01[j][ks], acc[i + 4][j], 0, 0, 0);
    __builtin_amdgcn_s_setprio(0);

    // tile boundary: T+1 must be fully staged; T+2.A may stay in flight
    if (t + 1 < nt) {
      if (t + 2 < nt) asm volatile("s_waitcnt vmcnt(4)" ::: "memory");
      else            asm volatile("s_waitcnt vmcnt(0)" ::: "memory");
      __builtin_amdgcn_sched_barrier(0);
      __builtin_amdgcn_s_barrier();
    }
  }

  float bv[4];
#pragma unroll
  for (int j = 0; j < 4; ++j) bv[j] = bias[bn + wn + j * 16 + ln];
#pragma unroll
  for (int i = 0; i < 8; ++i)
#pragma unroll
    for (int j = 0; j < 4; ++j)
#pragma unroll
      for (int r = 0; r < 4; ++r) {
        const int row = bm + wm + i * 16 + quad * 4 + r;   // C: row=quad*4+reg
        const int col = bn + wn + j * 16 + ln;             //    col=lane&15
        const float val = acc[i][j][r] + bv[j];
        if (Ch) Ch[(size_t)row * N + col] = (f16)val;
        else    Cf[(size_t)row * N + col] = val;
      }
}

// ---------------------------------------------------------------------------
// rope_convert: fp16 qkv -> RoPE'd Qb/Kb, head-major [h][t][96] ZERO-PADDED
// (cols 80..95). Softmax scale folded into Qb. Vectorized (G13), 1 wave/token.
// ---------------------------------------------------------------------------
__global__ __launch_bounds__(256) void rope_convert(
    const f16* __restrict__ qkv, const float* __restrict__ cosb,
    const float* __restrict__ sinb, f16* __restrict__ Qb, f16* __restrict__ Kb) {
  const int tid = threadIdx.x;
  const int wave = tid >> 6, lane = tid & 63;
  const int t = blockIdx.x * 4 + wave;
  const size_t rowb = (size_t)t * N3_;
  const float qscale = 0.11180339887498949f;
#pragma unroll
  for (int u = 0; u < 5; ++u) {
    const int g = u * 64 + lane;          // chunk id 0..319 within token
    const int e = g * 8;                  // element 0..2552 (q then k)
    const int d = e % HD_;                // multiple of 8
    const int h = (e % D_HID) / HD_;
    const bool isK = e >= D_HID;
    const bool lo = d < 40;
    const int pe = lo ? e + 40 : e - 40;  // rotate_half partner chunk
    f16 v[8], p[8];
    *(int4*)v = *(const int4*)(qkv + rowb + e);
    *(int4*)p = *(const int4*)(qkv + rowb + pe);
    const float4 cs0 = *(const float4*)(cosb + (size_t)t * HD_ + d);
    const float4 cs1 = *(const float4*)(cosb + (size_t)t * HD_ + d + 4);
    const float4 sn0 = *(const float4*)(sinb + (size_t)t * HD_ + d);
    const float4 sn1 = *(const float4*)(sinb + (size_t)t * HD_ + d + 4);
    const float cs[8] = {cs0.x, cs0.y, cs0.z, cs0.w, cs1.x, cs1.y, cs1.z, cs1.w};
    const float sn[8] = {sn0.x, sn0.y, sn0.z, sn0.w, sn1.x, sn1.y, sn1.z, sn1.w};
    f16 o[8];
#pragma unroll
    for (int j = 0; j < 8; ++j) {
      const float pv = lo ? -(float)p[j] : (float)p[j];
      const float ov = (float)v[j] * cs[j] + pv * sn[j];
      o[j] = (f16)(isK ? ov : ov * qscale);
    }
    *(int4*)((isK ? Kb : Qb) + ((size_t)h * T_TOK + t) * QPAD + d) = *(const int4*)o;
  }
  // zero pad columns 80..95 (ws is poisoned): 64 lanes = 2(qk) x 16(h) x 2(half)
  {
    const int qk = lane >> 5, h = (lane >> 1) & 15, half = lane & 1;
    f16* dst = (qk ? Kb : Qb) + ((size_t)h * T_TOK + t) * QPAD + 80 + half * 8;
    *(int4*)dst = make_int4(0, 0, 0, 0);
  }
}

// ---------------------------------------------------------------------------
// vt_convert: v (fp16, cols 2560..3839 of qkv) -> Vt[h][d][t] (transposed).
// ---------------------------------------------------------------------------
__global__ __launch_bounds__(256) void vt_convert(const f16* __restrict__ qkv,
                                                  f16* __restrict__ Vt) {
  __shared__ f16 tl[HD_][136];
  const int h = blockIdx.x & 15;
  const int t0 = (blockIdx.x >> 4) * 128;
  const int tid = threadIdx.x;
#pragma unroll
  for (int it = 0; it < 5; ++it) {
    const int e = tid + it * 256;
    const int t = e / 10, pc = e % 10;
    int4 v = *(const int4*)(qkv + (size_t)(t0 + t) * N3_ + 2 * D_HID + h * HD_ + pc * 8);
    f16 tmp[8];
    *(int4*)tmp = v;
#pragma unroll
    for (int u = 0; u < 8; ++u) tl[pc * 8 + u][t] = tmp[u];
  }
  __syncthreads();
#pragma unroll
  for (int it = 0; it < 5; ++it) {
    const int e = tid + it * 256;
    const int d = e >> 4, pt = e & 15;
    *(int4*)(Vt + ((size_t)h * HD_ + d) * T_TOK + t0 + pt * 8) = *(const int4*)&tl[d][pt * 8];
  }
}

// ---------------------------------------------------------------------------
// attn_flash: BARRIER-FREE flash attention, T5 setprio (unchanged).
// ---------------------------------------------------------------------------
__global__ __launch_bounds__(256, 2) void attn_flash(
    const f16* __restrict__ Qb, const f16* __restrict__ Kb,
    const f16* __restrict__ Vt, f16* __restrict__ Oa) {
  __shared__ f16 Ps[4][64][72];              // per-wave P tile, stride 72
  const int tid = threadIdx.x;
  const int wave = tid >> 6, lane = tid & 63;
  const int quad = lane >> 4, ln = lane & 15;
  const int h = blockIdx.x & 15;
  const int qb = (blockIdx.x >> 4) & 3;
  const int c = blockIdx.x >> 6;
  const int t0 = c * L_ + qb * 256 + wave * 64;
  const size_t hb = (size_t)h * T_TOK;

  h8 aq[4][3];
#pragma unroll
  for (int i = 0; i < 4; ++i)
#pragma unroll
    for (int ks = 0; ks < 3; ++ks)
      aq[i][ks] = *(const h8*)(Qb + (hb + t0 + i * 16 + ln) * QPAD + ks * 32 + quad * 8);

  f32x4 o[4][5];
  float lsum[4][4];
#pragma unroll
  for (int i = 0; i < 4; ++i) {
#pragma unroll
    for (int jn = 0; jn < 5; ++jn) o[i][jn] = (f32x4){0.f, 0.f, 0.f, 0.f};
#pragma unroll
    for (int r = 0; r < 4; ++r) lsum[i][r] = 0.f;
  }

  for (int kb = 0; kb < 16; ++kb) {
    const int kt0 = c * L_ + kb * 64;
#pragma unroll
    for (int j = 0; j < 4; ++j) {
      h8 bk[3];
#pragma unroll
      for (int ks = 0; ks < 3; ++ks)
        bk[ks] = *(const h8*)(Kb + (hb + kt0 + j * 16 + ln) * QPAD + ks * 32 + quad * 8);
      f32x4 s[4];
#pragma unroll
      for (int i = 0; i < 4; ++i) s[i] = (f32x4){0.f, 0.f, 0.f, 0.f};
      __builtin_amdgcn_s_setprio(1);
#pragma unroll
      for (int ks = 0; ks < 3; ++ks)
#pragma unroll
        for (int i = 0; i < 4; ++i)
          s[i] = __builtin_amdgcn_mfma_f32_16x16x32_f16(aq[i][ks], bk[ks], s[i], 0, 0, 0);
      __builtin_amdgcn_s_setprio(0);
#pragma unroll
      for (int i = 0; i < 4; ++i)
#pragma unroll
        for (int r = 0; r < 4; ++r) {
          const float p = __expf(s[i][r]);
          lsum[i][r] += p;
          Ps[wave][i * 16 + quad * 4 + r][j * 16 + ln] = (f16)p;
        }
    }
#pragma unroll
    for (int ks = 0; ks < 2; ++ks) {
      h8 ap[4];
#pragma unroll
      for (int i = 0; i < 4; ++i)
        ap[i] = *(const h8*)&Ps[wave][i * 16 + ln][ks * 32 + quad * 8];
#pragma unroll
      for (int jn = 0; jn < 5; ++jn) {
        const h8 bv = *(const h8*)(Vt + ((size_t)h * HD_ + jn * 16 + ln) * T_TOK
                                   + kt0 + ks * 32 + quad * 8);
        __builtin_amdgcn_s_setprio(1);
#pragma unroll
        for (int i = 0; i < 4; ++i)
          o[i][jn] = __builtin_amdgcn_mfma_f32_16x16x32_f16(ap[i], bv, o[i][jn], 0, 0, 0);
        __builtin_amdgcn_s_setprio(0);
      }
    }
  }

#pragma unroll
  for (int i = 0; i < 4; ++i)
#pragma unroll
    for (int r = 0; r < 4; ++r) {
      float s = lsum[i][r];
#pragma unroll
      for (int off = 1; off < 16; off <<= 1) s += __shfl_xor(s, off);
      lsum[i][r] = 1.f / s;
    }

#pragma unroll
  for (int i = 0; i < 4; ++i)
#pragma unroll
    for (int r = 0; r < 4; ++r) {
      const int t = t0 + i * 16 + quad * 4 + r;
      const float inv = lsum[i][r];
#pragma unroll
      for (int jn = 0; jn < 5; ++jn)
        Oa[(size_t)t * D_HID + h * HD_ + jn * 16 + ln] = (f16)(o[i][jn][r] * inv);
    }
}

// ---------------------------------------------------------------------------
extern "C" void kernel_launch(void* const* d_in, const int* in_sizes, int n_in,
                              void* d_out, int out_size, void* d_ws, size_t ws_size,
                              hipStream_t stream) {
  (void)in_sizes; (void)n_in; (void)out_size; (void)ws_size;
  const float* x      = (const float*)d_in[0];
  const float* cosb   = (const float*)d_in[1];
  const float* sinb   = (const float*)d_in[2];
  const float* w_qkv  = (const float*)d_in[3];
  const float* b_qkv  = (const float*)d_in[4];
  const float* w_proj = (const float*)d_in[5];
  const float* b_proj = (const float*)d_in[6];
  float* out = (float*)d_out;

  // workspace map (bytes):
  //  [0)           qkv f16    62,914,560  } aliased by attn O (21 MB) post-vt
  //  [62914560)    Qb [16][8192][96]  25,165,824
  //  [88080384)    Kb [16][8192][96]  25,165,824
  //  [113246208)   Vt [16][80][8192]  20,971,520
  //  [134217728)   Wqkv_t              9,830,400
  //  [144048128)   Wproj_t             3,276,800   -> end 147,324,928
  char* ws = (char*)d_ws;
  f16* qkv_h  = (f16*)(ws);
  f16* attn_h = (f16*)(ws);                          // alias (post-attention)
  f16* x_h    = (f16*)(ws + 62914560);               // temp in Qb slot
  f16* Qb     = (f16*)(ws + 62914560);               // alias (post-GEMM1)
  f16* Kb     = (f16*)(ws + 88080384);
  f16* Vt     = (f16*)(ws + 113246208);
  f16* wq_t   = (f16*)(ws + 134217728);
  f16* wp_t   = (f16*)(ws + 144048128);

  // 1) fp16 conversions (X, W^T)
  convert_x<<<(T_TOK * D_HID / 4) / 256, 256, 0, stream>>>(x, x_h);
  convert_w_t<<<dim3(N3_ / 32, D_HID / 32), 256, 0, stream>>>(w_qkv, wq_t, D_HID, N3_);
  convert_w_t<<<dim3(D_HID / 32, D_HID / 32), 256, 0, stream>>>(w_proj, wp_t, D_HID, D_HID);
  // 2) qkv = x @ w_qkv + b_qkv  (fp16 out): 256x256 tiles, 480 blocks
  gemm_f16<<<(N3_ / 256) * (T_TOK / 256), 512, 0, stream>>>(
      x_h, wq_t, b_qkv, nullptr, qkv_h, T_TOK, N3_, D_HID);
  // 3) RoPE + head-major padded fp16 Q/K (scale folded into Q), 1 wave/token
  rope_convert<<<T_TOK / 4, 256, 0, stream>>>(qkv_h, cosb, sinb, Qb, Kb);
  // 4) V transpose to [h][d][t]
  vt_convert<<<H_ * (T_TOK / 128), 256, 0, stream>>>(qkv_h, Vt);
  // 5) barrier-free flash attention -> attn fp16 [t][1280]
  attn_flash<<<C_ * 4 * H_, 256, 0, stream>>>(Qb, Kb, Vt, attn_h);
  // 6) out = attn @ w_proj + b_proj  (fp32 out): 160 blocks
  gemm_f16<<<(D_HID / 256) * (T_TOK / 256), 512, 0, stream>>>(
      attn_h, wp_t, b_proj, out, nullptr, T_TOK, D_HID, D_HID);
}